// Round 7
// baseline (2645.187 us; speedup 1.0000x reference)
//
#include <hip/hip_runtime.h>
#include <math.h>

#define B_    64
#define T_    256
#define N_    61
#define FIN_  3
#define GH_   64
#define LH_   128
#define NC_   10
#define NG_   3904      /* N_*GH_ */
#define M_TOT 16384     /* B_*T_  */
#define CHUNK_M 8192

typedef __attribute__((ext_vector_type(8))) short bf16x8;
typedef __attribute__((ext_vector_type(4))) float f32x4;

__device__ __forceinline__ float gelu_exact(float x) {
    return 0.5f * x * (1.0f + erff(x * 0.70710678118654752f));
}
__device__ __forceinline__ float sigmoidf_(float x) {
    return 1.0f / (1.0f + expf(-x));
}
__device__ __forceinline__ unsigned short f2bf(float f) {
    unsigned int u = __float_as_uint(f);
    u = (u + 0x7FFFu + ((u >> 16) & 1u)) >> 16;
    return (unsigned short)u;
}
__device__ __forceinline__ void store_h(float* p, float v) { *p = v; }
__device__ __forceinline__ void store_h(unsigned short* p, float v) { *p = f2bf(v); }

__device__ __forceinline__ void gload_lds16(const void* g, void* l) {
    __builtin_amdgcn_global_load_lds(
        (const __attribute__((address_space(1))) unsigned int*)g,
        (__attribute__((address_space(3))) unsigned int*)l,
        16, 0, 0);
}

// ---------------------------------------------------------------------------
// fp32 -> bf16 weight conversion (4 elems/thread). n4 = ELEMENT count / 4.
// ---------------------------------------------------------------------------
__global__ __launch_bounds__(256) void cvt_bf16_kernel(
    const float* __restrict__ in, unsigned short* __restrict__ out, int n4)
{
    int i = blockIdx.x * 256 + threadIdx.x;
    if (i < n4) {
        float4 v = reinterpret_cast<const float4*>(in)[i];
        ushort4 o;
        o.x = f2bf(v.x); o.y = f2bf(v.y); o.z = f2bf(v.z); o.w = f2bf(v.w);
        reinterpret_cast<ushort4*>(out)[i] = o;
    }
}

// ---------------------------------------------------------------------------
// GCN: one block per (b,t). Register-tiled (4n x 4c per thread), float4 LDS
// reads, 64 FMAs per 8 LDS ops in the two heavy stages. fp32 throughout.
// LDS = 65,504 B (2 blocks/CU).
// ---------------------------------------------------------------------------
__global__ __launch_bounds__(256) void gcn_kernel(
    const float* __restrict__ x, const float* __restrict__ adj,
    const float* __restrict__ W1, const float* __restrict__ b1,
    const float* __restrict__ W2, const float* __restrict__ b2,
    unsigned short* __restrict__ seqc, int m_base)
{
    __shared__ __align__(16) float adjs[N_ * 64];   // [n][m] stride 64 (cols 61..63 = 0)
    __shared__ __align__(16) float h1s [N_ * 64];   // [m][c] stride 64
    __shared__ __align__(16) float w2t [64 * 65];   // [f][c] stride 65 (bank-safe)
    __shared__ __align__(16) float uni [N_ * 64];   // axs (61*3) then ah1s [n][c]
    __shared__ __align__(16) float xs  [184];
    __shared__ __align__(16) float w1s [192];
    __shared__ float b1s[64], b2s[64];

    const int tid = threadIdx.x;
    const int bt  = m_base + blockIdx.x;
    const int nq  = tid >> 4;           // 0..15 -> rows n = nq*4..nq*4+3
    const int cq  = tid & 15;           // 0..15 -> cols c = cq*4..cq*4+3

    // ---- staging
    for (int i = tid; i < N_ * 64; i += 256) {
        int n = i >> 6, m = i & 63;
        adjs[i] = (m < N_) ? adj[n * N_ + m] : 0.f;
    }
    for (int i = tid; i < N_ * FIN_; i += 256) xs[i] = x[(size_t)bt * (N_ * FIN_) + i];
    for (int i = tid; i < GH_ * FIN_; i += 256) w1s[i] = W1[i];
    if (tid < GH_) { b1s[tid] = b1[tid]; b2s[tid] = b2[tid]; }
    for (int i = tid; i < GH_ * GH_; i += 256) {
        int c = i >> 6, f = i & 63;
        w2t[f * 65 + c] = W2[i];        // transposed stage, stride 65
    }
    __syncthreads();

    // ---- AX (61x3) -> uni[0..182]
    if (tid < N_ * FIN_) {
        int n = tid / 3, f = tid - n * 3;
        float acc = 0.f;
        for (int m = 0; m < N_; ++m) acc += adjs[n * 64 + m] * xs[m * 3 + f];
        uni[tid] = acc;
    }
    __syncthreads();

    const int n0  = nq * 4;
    const int nr0 = (n0     < N_) ? n0     : N_ - 1;
    const int nr1 = (n0 + 1 < N_) ? n0 + 1 : N_ - 1;
    const int nr2 = (n0 + 2 < N_) ? n0 + 2 : N_ - 1;
    const int nr3 = (n0 + 3 < N_) ? n0 + 3 : N_ - 1;
    const int nr[4] = {nr0, nr1, nr2, nr3};

    // ---- H1 = gelu(AX @ W1^T + b1) -> h1s[m][c]  (K=3, cheap)
    {
        float h[4][4];
        #pragma unroll
        for (int i = 0; i < 4; ++i) {
            #pragma unroll
            for (int j = 0; j < 4; ++j) {
                int c = cq * 4 + j;
                float acc = b1s[c];
                #pragma unroll
                for (int f = 0; f < 3; ++f) acc += uni[nr[i] * 3 + f] * w1s[c * 3 + f];
                h[i][j] = gelu_exact(acc);
            }
        }
        #pragma unroll
        for (int i = 0; i < 4; ++i) {
            int n = n0 + i;
            if (n < N_) {
                float4 v = {h[i][0], h[i][1], h[i][2], h[i][3]};
                *reinterpret_cast<float4*>(&h1s[n * 64 + cq * 4]) = v;
            }
        }
    }
    __syncthreads();   // h1s ready; uni reads done (safe to overwrite below)

    // ---- AH1 = A @ H1 : 4x4 register tile, K=61 blocked 15x4 + 1 tail
    {
        float acc[4][4];
        #pragma unroll
        for (int i = 0; i < 4; ++i)
            #pragma unroll
            for (int j = 0; j < 4; ++j) acc[i][j] = 0.f;

        for (int m4 = 0; m4 < 15; ++m4) {
            float4 a[4], hv[4];
            #pragma unroll
            for (int i = 0; i < 4; ++i)
                a[i] = *reinterpret_cast<const float4*>(&adjs[nr[i] * 64 + m4 * 4]);
            #pragma unroll
            for (int k = 0; k < 4; ++k)
                hv[k] = *reinterpret_cast<const float4*>(&h1s[(m4 * 4 + k) * 64 + cq * 4]);
            #pragma unroll
            for (int i = 0; i < 4; ++i) {
                acc[i][0] += a[i].x * hv[0].x + a[i].y * hv[1].x + a[i].z * hv[2].x + a[i].w * hv[3].x;
                acc[i][1] += a[i].x * hv[0].y + a[i].y * hv[1].y + a[i].z * hv[2].y + a[i].w * hv[3].y;
                acc[i][2] += a[i].x * hv[0].z + a[i].y * hv[1].z + a[i].z * hv[2].z + a[i].w * hv[3].z;
                acc[i][3] += a[i].x * hv[0].w + a[i].y * hv[1].w + a[i].z * hv[2].w + a[i].w * hv[3].w;
            }
        }
        {   // tail m = 60
            float4 hv = *reinterpret_cast<const float4*>(&h1s[60 * 64 + cq * 4]);
            #pragma unroll
            for (int i = 0; i < 4; ++i) {
                float av = adjs[nr[i] * 64 + 60];
                acc[i][0] += av * hv.x; acc[i][1] += av * hv.y;
                acc[i][2] += av * hv.z; acc[i][3] += av * hv.w;
            }
        }
        #pragma unroll
        for (int i = 0; i < 4; ++i) {
            int n = n0 + i;
            if (n < N_) {
                float4 v = {acc[i][0], acc[i][1], acc[i][2], acc[i][3]};
                *reinterpret_cast<float4*>(&uni[n * 64 + cq * 4]) = v;  // ah1s[n][c]
            }
        }
    }
    __syncthreads();

    // ---- H2 = gelu(AH1 @ W2^T + b2) -> seq bf16 : K=64 blocked 16x4
    {
        float acc[4][4];
        #pragma unroll
        for (int i = 0; i < 4; ++i)
            #pragma unroll
            for (int j = 0; j < 4; ++j) acc[i][j] = b2s[cq * 4 + j];

        for (int f4 = 0; f4 < 16; ++f4) {
            float4 a[4], wv[4];
            #pragma unroll
            for (int i = 0; i < 4; ++i)
                a[i] = *reinterpret_cast<const float4*>(&uni[nr[i] * 64 + f4 * 4]);
            #pragma unroll
            for (int k = 0; k < 4; ++k)
                wv[k] = *reinterpret_cast<const float4*>(&w2t[(f4 * 4 + k) * 65 + cq * 4]);
            #pragma unroll
            for (int i = 0; i < 4; ++i) {
                acc[i][0] += a[i].x * wv[0].x + a[i].y * wv[1].x + a[i].z * wv[2].x + a[i].w * wv[3].x;
                acc[i][1] += a[i].x * wv[0].y + a[i].y * wv[1].y + a[i].z * wv[2].y + a[i].w * wv[3].y;
                acc[i][2] += a[i].x * wv[0].z + a[i].y * wv[1].z + a[i].z * wv[2].z + a[i].w * wv[3].z;
                acc[i][3] += a[i].x * wv[0].w + a[i].y * wv[1].w + a[i].z * wv[2].w + a[i].w * wv[3].w;
            }
        }
        #pragma unroll
        for (int i = 0; i < 4; ++i) {
            int n = n0 + i;
            if (n < N_) {
                ushort4 o;
                o.x = f2bf(gelu_exact(acc[i][0]));
                o.y = f2bf(gelu_exact(acc[i][1]));
                o.z = f2bf(gelu_exact(acc[i][2]));
                o.w = f2bf(gelu_exact(acc[i][3]));
                *reinterpret_cast<ushort4*>(&seqc[(size_t)blockIdx.x * NG_ + n * 64 + cq * 4]) = o;
            }
        }
    }
}

// ---------------------------------------------------------------------------
// bf16 MFMA GEMM: C = A(Mc x K) @ W(1024 x K)^T + bias_a + bias_b
// 128x128 tile, 4 waves (2x2), 16x16x32 MFMA, BK=32, global_load_lds staging.
// Output scattered fp32 to [d][Mtot][512].
// ---------------------------------------------------------------------------
__global__ __launch_bounds__(256) void gemm_mfma_kernel(
    const unsigned short* __restrict__ A, const unsigned short* __restrict__ W,
    const float* __restrict__ bias_a, const float* __restrict__ bias_b,
    float* __restrict__ Cout, int K, int m_base, int Mtot)
{
    __shared__ unsigned short As[128 * 32];   // 8 KB, row-major [row][k], 64B/row
    __shared__ unsigned short Bs[128 * 32];   // 8 KB

    const int tid = threadIdx.x;
    const int w   = tid >> 6;            // wave 0..3
    const int l   = tid & 63;
    const int wr  = w >> 1, wc = w & 1;  // 2x2 wave grid, each wave 64x64
    const int lr  = l & 15, lk = l >> 4;

    const int m0 = blockIdx.x * 128;
    const int n0 = blockIdx.y * 128;

    f32x4 acc[4][4];
    #pragma unroll
    for (int i = 0; i < 4; ++i)
        #pragma unroll
        for (int j = 0; j < 4; ++j) acc[i][j] = (f32x4){0.f, 0.f, 0.f, 0.f};

    // staging: thread tid covers LDS bytes [tid*16, tid*16+16) == row tid>>2,
    // cols (tid&3)*8..+7  (linear [row][k] layout, 64 B/row)
    const int row_a0 = tid >> 2;
    const int cb     = (tid & 3) * 8;
    const unsigned short* aptr0 = A + (size_t)(m0 + row_a0) * K + cb;
    const unsigned short* aptr1 = A + (size_t)(m0 + row_a0 + 64) * K + cb;
    const unsigned short* bptr0 = W + (size_t)(n0 + row_a0) * K + cb;
    const unsigned short* bptr1 = W + (size_t)(n0 + row_a0 + 64) * K + cb;
    unsigned short* lA0 = &As[w * 512];               // wave-uniform LDS bases
    unsigned short* lA1 = &As[2048 + w * 512];
    unsigned short* lB0 = &Bs[w * 512];
    unsigned short* lB1 = &Bs[2048 + w * 512];

    for (int k0 = 0; k0 < K; k0 += 32) {
        gload_lds16(aptr0 + k0, lA0);
        gload_lds16(aptr1 + k0, lA1);
        gload_lds16(bptr0 + k0, lB0);
        gload_lds16(bptr1 + k0, lB1);
        __syncthreads();

        bf16x8 af[4], bfr[4];
        #pragma unroll
        for (int i = 0; i < 4; ++i)
            af[i] = *reinterpret_cast<const bf16x8*>(&As[(wr * 64 + i * 16 + lr) * 32 + lk * 8]);
        #pragma unroll
        for (int j = 0; j < 4; ++j)
            bfr[j] = *reinterpret_cast<const bf16x8*>(&Bs[(wc * 64 + j * 16 + lr) * 32 + lk * 8]);
        #pragma unroll
        for (int i = 0; i < 4; ++i)
            #pragma unroll
            for (int j = 0; j < 4; ++j)
                acc[i][j] = __builtin_amdgcn_mfma_f32_16x16x32_bf16(af[i], bfr[j], acc[i][j], 0, 0, 0);
        __syncthreads();
    }

    // epilogue: D lane map col=l&15 (n), row=(l>>4)*4+r (m)
    #pragma unroll
    for (int i = 0; i < 4; ++i) {
        #pragma unroll
        for (int j = 0; j < 4; ++j) {
            int n = n0 + wc * 64 + j * 16 + lr;
            float ba = bias_a[n] + bias_b[n];
            int d = n >> 9, g = n & 511;
            #pragma unroll
            for (int r = 0; r < 4; ++r) {
                int m = m_base + m0 + wr * 64 + i * 16 + lk * 4 + r;
                Cout[((size_t)d * Mtot + m) * 512 + g] = acc[i][j][r] + ba;
            }
        }
    }
}

// ---------------------------------------------------------------------------
// BiLSTM recurrence: one block per (dir,batch). 1024 threads.
// ---------------------------------------------------------------------------
template <typename OT>
__global__ __launch_bounds__(1024) void lstm_kernel(
    const float* __restrict__ pre,   // [d][b][t][512]
    const float* __restrict__ Whh,   // [2][512][128]
    OT* __restrict__ hout)           // [b][t][256]
{
    const int d   = blockIdx.x >> 6;
    const int b   = blockIdx.x & 63;
    const int tid = threadIdx.x;
    const int g   = tid & 511;
    const int kh  = tid >> 9;

    float w[64];
    const float* wsrc = Whh + ((size_t)d * 512 + g) * 128 + kh * 64;
    #pragma unroll
    for (int k = 0; k < 64; ++k) w[k] = wsrc[k];

    __shared__ __align__(16) float h_lds[128];
    __shared__ float part[1024];
    __shared__ float gates[512];

    if (tid < 128) h_lds[tid] = 0.f;
    float c = 0.f;
    __syncthreads();

    const float* prebase = pre + ((size_t)(d * B_ + b)) * T_ * 512;

    for (int s = 0; s < T_; ++s) {
        int t = d ? (T_ - 1 - s) : s;
        float p = (tid < 512) ? prebase[(size_t)t * 512 + g] : 0.f;

        float acc0 = 0.f, acc1 = 0.f;
        #pragma unroll
        for (int k4 = 0; k4 < 16; ++k4) {
            float4 hv = *reinterpret_cast<const float4*>(&h_lds[kh * 64 + k4 * 4]);
            acc0 += w[k4 * 4 + 0] * hv.x; acc1 += w[k4 * 4 + 1] * hv.y;
            acc0 += w[k4 * 4 + 2] * hv.z; acc1 += w[k4 * 4 + 3] * hv.w;
        }
        part[tid] = acc0 + acc1;
        __syncthreads();
        if (tid < 512) gates[g] = p + part[g] + part[g + 512];
        __syncthreads();
        if (tid < 128) {
            float gi = gates[tid], gf = gates[tid + 128];
            float gc = gates[tid + 256], go = gates[tid + 384];
            c = sigmoidf_(gf) * c + sigmoidf_(gi) * tanhf(gc);
            float h = sigmoidf_(go) * tanhf(c);
            h_lds[tid] = h;
            store_h(&hout[((size_t)b * T_ + t) * 256 + d * 128 + tid], h);
        }
        __syncthreads();
    }
}

// ---------------------------------------------------------------------------
// attention scores: block per b.
// ---------------------------------------------------------------------------
__global__ __launch_bounds__(256) void attn_scores_kernel(
    const float* __restrict__ l1, const float* __restrict__ Wa1,
    const float* __restrict__ ba1, const float* __restrict__ Wa2,
    const float* __restrict__ ba2, float* __restrict__ scores)
{
    const int b   = blockIdx.x;
    const int tid = threadIdx.x;
    const int j   = tid & 63, kq = tid >> 6;

    float w[64];
    const float* wsrc = Wa1 + j * 256 + kq * 64;
    #pragma unroll
    for (int k = 0; k < 64; ++k) w[k] = wsrc[k];

    __shared__ __align__(16) float row[256];
    __shared__ float part[256];
    const float* lb  = l1 + (size_t)b * T_ * 256;
    float wa2 = (tid < 64) ? Wa2[tid] : 0.f;
    float bj  = (tid < 64) ? ba1[tid] : 0.f;
    float bb2 = ba2[0];

    for (int t = 0; t < T_; ++t) {
        __syncthreads();
        row[tid] = lb[(size_t)t * 256 + tid];
        __syncthreads();
        float acc = 0.f;
        #pragma unroll
        for (int k4 = 0; k4 < 16; ++k4) {
            float4 hv = *reinterpret_cast<const float4*>(&row[kq * 64 + k4 * 4]);
            acc += w[k4 * 4 + 0] * hv.x + w[k4 * 4 + 1] * hv.y
                 + w[k4 * 4 + 2] * hv.z + w[k4 * 4 + 3] * hv.w;
        }
        part[tid] = acc;
        __syncthreads();
        if (tid < 64) {
            float dj = part[tid] + part[tid + 64] + part[tid + 128] + part[tid + 192];
            float sv = tanhf(dj + bj) * wa2;
            #pragma unroll
            for (int off = 32; off > 0; off >>= 1) sv += __shfl_xor(sv, off);
            if (tid == 0) scores[b * T_ + t] = sv + bb2;
        }
    }
}

// ---------------------------------------------------------------------------
// softmax + context + classifier head: block per b.
// ---------------------------------------------------------------------------
__global__ __launch_bounds__(256) void attn_head_kernel(
    const float* __restrict__ l1, const float* __restrict__ scores,
    const float* __restrict__ Wc1, const float* __restrict__ bc1,
    const float* __restrict__ Wc2, const float* __restrict__ bc2,
    float* __restrict__ out)
{
    const int b   = blockIdx.x;
    const int tid = threadIdx.x;
    __shared__ float wsl[256];
    __shared__ float red[8];
    __shared__ float ctx[256];
    __shared__ float hid[128];
    __shared__ float wc1s[128 * 65];

    float v = scores[b * T_ + tid];
    float mx = v;
    #pragma unroll
    for (int off = 32; off > 0; off >>= 1) mx = fmaxf(mx, __shfl_xor(mx, off));
    if ((tid & 63) == 0) red[tid >> 6] = mx;
    __syncthreads();
    mx = fmaxf(fmaxf(red[0], red[1]), fmaxf(red[2], red[3]));
    float e = expf(v - mx);
    float s = e;
    #pragma unroll
    for (int off = 32; off > 0; off >>= 1) s += __shfl_xor(s, off);
    if ((tid & 63) == 0) red[4 + (tid >> 6)] = s;
    __syncthreads();
    float denom = red[4] + red[5] + red[6] + red[7];
    wsl[tid] = e / denom;
    __syncthreads();

    float acc = 0.f;
    const float* lb = l1 + (size_t)b * T_ * 256 + tid;
    #pragma unroll 4
    for (int t = 0; t < T_; ++t) acc += lb[(size_t)t * 256] * wsl[t];
    ctx[tid] = acc;
    __syncthreads();

    float hacc = (tid < 128) ? bc1[tid] : 0.f;
    for (int kb = 0; kb < 4; ++kb) {
        for (int i = tid; i < 128 * 64; i += 256) {
            int jj = i >> 6, kk = i & 63;
            wc1s[jj * 65 + kk] = Wc1[jj * 256 + kb * 64 + kk];
        }
        __syncthreads();
        if (tid < 128) {
            #pragma unroll
            for (int kk = 0; kk < 64; ++kk)
                hacc += ctx[kb * 64 + kk] * wc1s[tid * 65 + kk];
        }
        __syncthreads();
    }
    if (tid < 128) hid[tid] = fmaxf(hacc, 0.f);
    __syncthreads();

    if (tid < NC_) {
        float a = bc2[tid];
        #pragma unroll
        for (int k = 0; k < 128; ++k) a += hid[k] * Wc2[tid * 128 + k];
        out[b * NC_ + tid] = a;
    }
}

// ---------------------------------------------------------------------------
extern "C" void kernel_launch(void* const* d_in, const int* in_sizes, int n_in,
                              void* d_out, int out_size, void* d_ws, size_t ws_size,
                              hipStream_t stream)
{
    const float* x    = (const float*)d_in[0];
    const float* adj  = (const float*)d_in[1];
    const float* Wg1  = (const float*)d_in[2];
    const float* bg1  = (const float*)d_in[3];
    const float* Wg2  = (const float*)d_in[4];
    const float* bg2  = (const float*)d_in[5];
    const float* Wih0 = (const float*)d_in[6];
    const float* Whh0 = (const float*)d_in[7];
    const float* bih0 = (const float*)d_in[8];
    const float* bhh0 = (const float*)d_in[9];
    const float* Wih1 = (const float*)d_in[10];
    const float* Whh1 = (const float*)d_in[11];
    const float* bih1 = (const float*)d_in[12];
    const float* bhh1 = (const float*)d_in[13];
    const float* Wa1  = (const float*)d_in[14];
    const float* ba1  = (const float*)d_in[15];
    const float* Wa2  = (const float*)d_in[16];
    const float* ba2  = (const float*)d_in[17];
    const float* Wc1  = (const float*)d_in[18];
    const float* bc1  = (const float*)d_in[19];
    const float* Wc2  = (const float*)d_in[20];
    const float* bc2  = (const float*)d_in[21];

    char* ws = (char*)d_ws;
    // Workspace layout (byte offsets, peak 142,737,408 B — proven fits).
    // Phase 1 (GCN + GEMM0 chunks): seqb [0, 63,963,136)
    // Phase 2+: l0b [0, 8,388,608)  l1f [8,388,608, 25,165,824)  scr [25,165,824, +64K)
    unsigned short* seqb = (unsigned short*)(ws);
    unsigned short* l0b  = (unsigned short*)(ws);
    float*          l1f  = (float*)(ws + 8388608);
    float*          scr  = (float*)(ws + 25165824);
    float*          pre  = (float*)(ws + 67108864);              // 67,108,864 B
    unsigned short* W0b  = (unsigned short*)(ws + 134217728);    // 7,995,392 B
    unsigned short* W1b  = (unsigned short*)(ws + 142213120);    // 524,288 B

    // weight conversions (bf16) — counts are ELEMENT counts from in_sizes
    const int n0e = in_sizes[6];    // 2*512*3904 = 3,997,696
    const int n1e = in_sizes[10];   // 2*512*256  = 262,144
    cvt_bf16_kernel<<<(n0e / 4 + 255) / 256, 256, 0, stream>>>(Wih0, W0b, n0e / 4);
    cvt_bf16_kernel<<<(n1e / 4 + 255) / 256, 256, 0, stream>>>(Wih1, W1b, n1e / 4);

    for (int ch = 0; ch < 2; ++ch) {
        int m_base = ch * CHUNK_M;
        gcn_kernel<<<CHUNK_M, 256, 0, stream>>>(x, adj, Wg1, bg1, Wg2, bg2, seqb, m_base);
        gemm_mfma_kernel<<<dim3(CHUNK_M / 128, 8), 256, 0, stream>>>(
            seqb, W0b, bih0, bhh0, pre, NG_, m_base, M_TOT);
    }
    lstm_kernel<<<128, 1024, 0, stream>>>(pre, Whh0, l0b);
    gemm_mfma_kernel<<<dim3(M_TOT / 128, 8), 256, 0, stream>>>(
        l0b, W1b, bih1, bhh1, pre, 256, 0, M_TOT);
    lstm_kernel<<<128, 1024, 0, stream>>>(pre, Whh1, l1f);
    attn_scores_kernel<<<B_, 256, 0, stream>>>(l1f, Wa1, ba1, Wa2, ba2, scr);
    attn_head_kernel<<<B_, 256, 0, stream>>>(l1f, scr, Wc1, bc1, Wc2, bc2, (float*)d_out);
}

// Round 8
// 1373.913 us; speedup vs baseline: 1.9253x; 1.9253x over previous
//
#include <hip/hip_runtime.h>
#include <math.h>

#define B_    64
#define T_    256
#define N_    61
#define FIN_  3
#define GH_   64
#define LH_   128
#define NC_   10
#define NG_   3904      /* N_*GH_ */
#define M_TOT 16384     /* B_*T_  */
#define CHUNK_M 8192
#define SUB_M   2048    /* GCN sub-chunk */

typedef __attribute__((ext_vector_type(8))) short bf16x8;
typedef __attribute__((ext_vector_type(4))) float f32x4;

__device__ __forceinline__ float gelu_exact(float x) {
    return 0.5f * x * (1.0f + erff(x * 0.70710678118654752f));
}
__device__ __forceinline__ float sigmoidf_(float x) {
    return 1.0f / (1.0f + expf(-x));
}
__device__ __forceinline__ unsigned short f2bf(float f) {
    unsigned int u = __float_as_uint(f);
    u = (u + 0x7FFFu + ((u >> 16) & 1u)) >> 16;
    return (unsigned short)u;
}
__device__ __forceinline__ void store_h(float* p, float v) { *p = v; }
__device__ __forceinline__ void store_h(unsigned short* p, float v) { *p = f2bf(v); }

__device__ __forceinline__ void gload_lds16(const void* g, void* l) {
    __builtin_amdgcn_global_load_lds(
        (const __attribute__((address_space(1))) unsigned int*)g,
        (__attribute__((address_space(3))) unsigned int*)l,
        16, 0, 0);
}

// Shared 64-elem-row swizzle: XOR k with (row&3)*16. Used identically by every
// writer (global pre-swizzle) and reader (LDS frag read) — both-sides-or-neither.
__device__ __forceinline__ int swz(int row, int k) { return k ^ ((row & 3) << 4); }

// ---------------------------------------------------------------------------
// fp32 -> bf16 weight conversion (4 elems/thread). n4 = ELEMENT count / 4.
// ---------------------------------------------------------------------------
__global__ __launch_bounds__(256) void cvt_bf16_kernel(
    const float* __restrict__ in, unsigned short* __restrict__ out, int n4)
{
    int i = blockIdx.x * 256 + threadIdx.x;
    if (i < n4) {
        float4 v = reinterpret_cast<const float4*>(in)[i];
        ushort4 o;
        o.x = f2bf(v.x); o.y = f2bf(v.y); o.z = f2bf(v.z); o.w = f2bf(v.w);
        reinterpret_cast<ushort4*>(out)[i] = o;
    }
}

// adj (61x61 fp32) -> adjb (64x64 bf16, zero-padded, pre-swizzled). grid 16.
__global__ __launch_bounds__(256) void cvt_adj_kernel(
    const float* __restrict__ adj, unsigned short* __restrict__ adjb)
{
    int i = blockIdx.x * 256 + threadIdx.x;
    if (i < 4096) {
        int n = i >> 6, m = i & 63;
        unsigned short v = (n < N_ && m < N_) ? f2bf(adj[n * N_ + m]) : (unsigned short)0;
        adjb[n * 64 + swz(n, m)] = v;
    }
}

// W2 (64x64 fp32) -> w2b (64x64 bf16, pre-swizzled). grid 16.
__global__ __launch_bounds__(256) void cvt_w2_kernel(
    const float* __restrict__ W2, unsigned short* __restrict__ w2b)
{
    int i = blockIdx.x * 256 + threadIdx.x;
    if (i < 4096) {
        int c = i >> 6, f = i & 63;
        w2b[c * 64 + swz(c, f)] = f2bf(W2[c * 64 + f]);
    }
}

// ---------------------------------------------------------------------------
// GCN K1: per (b,t): AX = A@X (fp32), H1 = gelu(AX @ W1^T + b1).
// Writes H1W bf16 TRANSPOSED [btl*64+c][m], m=61..63 zeroed, pre-swizzled.
// grid = SUB_M blocks.
// ---------------------------------------------------------------------------
__global__ __launch_bounds__(256) void gcn_h1_kernel(
    const float* __restrict__ x, const float* __restrict__ adj,
    const float* __restrict__ W1, const float* __restrict__ b1,
    unsigned short* __restrict__ H1W, int bt_base)
{
    __shared__ float adjs[N_ * 65];   // stride 65: conflict-free column walks
    __shared__ float h1s [N_ * 65];
    __shared__ float xs [184];
    __shared__ float axs[184];
    __shared__ float w1s[192];
    __shared__ float b1s[64];

    const int tid = threadIdx.x;
    const int bt  = bt_base + blockIdx.x;

    for (int i = tid; i < N_ * N_; i += 256) {
        int n = i / 61, m = i - n * 61;
        adjs[n * 65 + m] = adj[i];
    }
    for (int i = tid; i < N_ * FIN_; i += 256) xs[i] = x[(size_t)bt * (N_ * FIN_) + i];
    for (int i = tid; i < GH_ * FIN_; i += 256) w1s[i] = W1[i];
    if (tid < GH_) b1s[tid] = b1[tid];
    __syncthreads();

    if (tid < N_ * FIN_) {
        int n = tid / 3, f = tid - n * 3;
        float acc = 0.f;
        for (int m = 0; m < N_; ++m) acc += adjs[n * 65 + m] * xs[m * 3 + f];
        axs[tid] = acc;
    }
    __syncthreads();

    for (int u = 0; u < 16; ++u) {
        int idx = tid + u * 256;
        if (idx < N_ * GH_) {
            int m = idx >> 6, c = idx & 63;
            float acc = b1s[c];
            acc += axs[m * 3 + 0] * w1s[c * 3 + 0];
            acc += axs[m * 3 + 1] * w1s[c * 3 + 1];
            acc += axs[m * 3 + 2] * w1s[c * 3 + 2];
            h1s[m * 65 + c] = gelu_exact(acc);
        }
    }
    __syncthreads();

    // transposed, padded, pre-swizzled write: H1W[(btl*64+c)][swz(c,m)]
    unsigned short* dst = H1W + (size_t)blockIdx.x * 4096;
    for (int i = tid; i < 4096; i += 256) {
        int c = i >> 6, m = i & 63;
        unsigned short v = (m < N_) ? f2bf(h1s[m * 65 + c]) : (unsigned short)0;
        dst[c * 64 + swz(c, m)] = v;
    }
}

// ---------------------------------------------------------------------------
// GCN K23: per block = 2 consecutive bt. MFMA both heavy stages:
//   stage1: AH1[n][btc] = adjb(64x64) @ H1W-tile^T   (16x16x32, K=64, 16 MFMA/wave... 32 total... 8/wave x2)
//   bounce: AH1 -> T[(btl*64+n)][c] bf16 (swizzled)
//   stage2: seq = gelu(T @ W2^T + b2)
// grid = SUB_M/2 blocks, 256 threads (4 waves).
// ---------------------------------------------------------------------------
__global__ __launch_bounds__(256) void gcn_mix_kernel(
    const unsigned short* __restrict__ H1W,   // [SUB_M*64][64] pre-swizzled
    const unsigned short* __restrict__ adjb,  // [64][64] pre-swizzled
    const unsigned short* __restrict__ w2b,   // [64][64] pre-swizzled
    const float* __restrict__ b2,
    unsigned short* __restrict__ seqc,        // chunk-local [CHUNK_M][3904]
    int sc_base)                              // sub-chunk base within chunk
{
    __shared__ unsigned short adjbs[64 * 64];   // 8 KB
    __shared__ unsigned short b1t [128 * 64];   // 16 KB (H1W rows for 2 bt)
    __shared__ unsigned short w2bs[64 * 64];    // 8 KB
    __shared__ unsigned short T   [128 * 64];   // 16 KB (AH1 transposed)
    __shared__ float b2s[64];

    const int tid = threadIdx.x;
    const int w   = tid >> 6;
    const int l   = tid & 63;
    const int lr  = l & 15, lk = l >> 4;
    const int p   = blockIdx.x;               // bt pair

    // staging: linear copies (sources are pre-swizzled in global)
    #pragma unroll
    for (int q = 0; q < 2; ++q)
        gload_lds16(adjb + q * 2048 + w * 512 + l * 8, &adjbs[q * 2048 + w * 512]);
    #pragma unroll
    for (int q = 0; q < 2; ++q)
        gload_lds16(w2b + q * 2048 + w * 512 + l * 8, &w2bs[q * 2048 + w * 512]);
    #pragma unroll
    for (int q = 0; q < 4; ++q)
        gload_lds16(H1W + (size_t)p * 8192 + q * 2048 + w * 512 + l * 8,
                    &b1t[q * 2048 + w * 512]);
    if (tid < 64) b2s[tid] = b2[tid];
    __syncthreads();

    // ---- stage1: AH1[n][col], wave w owns cols w*32..w*32+31
    f32x4 acc1[4][2];
    #pragma unroll
    for (int i = 0; i < 4; ++i)
        #pragma unroll
        for (int j = 0; j < 2; ++j) acc1[i][j] = (f32x4){0.f, 0.f, 0.f, 0.f};

    #pragma unroll
    for (int kk = 0; kk < 2; ++kk) {
        const int kb = kk * 32 + lk * 8;
        bf16x8 af[4], bfr[2];
        #pragma unroll
        for (int i = 0; i < 4; ++i) {
            int rn = i * 16 + lr;
            af[i] = *reinterpret_cast<const bf16x8*>(&adjbs[rn * 64 + swz(rn, kb)]);
        }
        #pragma unroll
        for (int j = 0; j < 2; ++j) {
            int rb = w * 32 + j * 16 + lr;
            bfr[j] = *reinterpret_cast<const bf16x8*>(&b1t[rb * 64 + swz(rb, kb)]);
        }
        #pragma unroll
        for (int i = 0; i < 4; ++i)
            #pragma unroll
            for (int j = 0; j < 2; ++j)
                acc1[i][j] = __builtin_amdgcn_mfma_f32_16x16x32_bf16(af[i], bfr[j], acc1[i][j], 0, 0, 0);
    }

    // ---- bounce: AH1[n][col] -> T[(col>>6)*64 + n][col&63], bf16, swizzled.
    // Waves write disjoint (row,col) regions -> no barrier needed before writes.
    #pragma unroll
    for (int i = 0; i < 4; ++i) {
        #pragma unroll
        for (int j = 0; j < 2; ++j) {
            int col = w * 32 + j * 16 + lr;
            int c   = col & 63;
            int rbase = (col >> 6) * 64;
            #pragma unroll
            for (int r = 0; r < 4; ++r) {
                int n   = i * 16 + lk * 4 + r;
                int row = rbase + n;
                T[row * 64 + swz(row, c)] = f2bf(acc1[i][j][r]);
            }
        }
    }
    __syncthreads();

    // ---- stage2: rows (bt,n) = w*32.., cols cout
    f32x4 acc2[2][4];
    #pragma unroll
    for (int i = 0; i < 2; ++i)
        #pragma unroll
        for (int j = 0; j < 4; ++j) acc2[i][j] = (f32x4){0.f, 0.f, 0.f, 0.f};

    #pragma unroll
    for (int kk = 0; kk < 2; ++kk) {
        const int kb = kk * 32 + lk * 8;
        bf16x8 a2[2], bw[4];
        #pragma unroll
        for (int i = 0; i < 2; ++i) {
            int r2 = w * 32 + i * 16 + lr;
            a2[i] = *reinterpret_cast<const bf16x8*>(&T[r2 * 64 + swz(r2, kb)]);
        }
        #pragma unroll
        for (int j = 0; j < 4; ++j) {
            int co = j * 16 + lr;
            bw[j] = *reinterpret_cast<const bf16x8*>(&w2bs[co * 64 + swz(co, kb)]);
        }
        #pragma unroll
        for (int i = 0; i < 2; ++i)
            #pragma unroll
            for (int j = 0; j < 4; ++j)
                acc2[i][j] = __builtin_amdgcn_mfma_f32_16x16x32_bf16(a2[i], bw[j], acc2[i][j], 0, 0, 0);
    }

    // ---- epilogue: +b2, gelu, write seq rows (n<61 guard)
    #pragma unroll
    for (int i = 0; i < 2; ++i) {
        #pragma unroll
        for (int j = 0; j < 4; ++j) {
            int co = j * 16 + lr;
            float bias = b2s[co];
            #pragma unroll
            for (int r = 0; r < 4; ++r) {
                int row = w * 32 + i * 16 + lk * 4 + r;
                int n   = row & 63;
                if (n < N_) {
                    int btc = sc_base + p * 2 + (row >> 6);
                    seqc[(size_t)btc * NG_ + n * 64 + co] =
                        f2bf(gelu_exact(acc2[i][j][r] + bias));
                }
            }
        }
    }
}

// ---------------------------------------------------------------------------
// bf16 MFMA GEMM: C = A(Mc x K) @ W(1024 x K)^T + bias_a + bias_b
// 128x128 tile, 4 waves (2x2), 16x16x32 MFMA, BK=32, global_load_lds staging.
// Output scattered fp32 to [d][Mtot][512].
// ---------------------------------------------------------------------------
__global__ __launch_bounds__(256) void gemm_mfma_kernel(
    const unsigned short* __restrict__ A, const unsigned short* __restrict__ W,
    const float* __restrict__ bias_a, const float* __restrict__ bias_b,
    float* __restrict__ Cout, int K, int m_base, int Mtot)
{
    __shared__ unsigned short As[128 * 32];   // 8 KB, row-major [row][k], 64B/row
    __shared__ unsigned short Bs[128 * 32];   // 8 KB

    const int tid = threadIdx.x;
    const int w   = tid >> 6;
    const int l   = tid & 63;
    const int wr  = w >> 1, wc = w & 1;
    const int lr  = l & 15, lk = l >> 4;

    const int m0 = blockIdx.x * 128;
    const int n0 = blockIdx.y * 128;

    f32x4 acc[4][4];
    #pragma unroll
    for (int i = 0; i < 4; ++i)
        #pragma unroll
        for (int j = 0; j < 4; ++j) acc[i][j] = (f32x4){0.f, 0.f, 0.f, 0.f};

    const int row_a0 = tid >> 2;
    const int cb     = (tid & 3) * 8;
    const unsigned short* aptr0 = A + (size_t)(m0 + row_a0) * K + cb;
    const unsigned short* aptr1 = A + (size_t)(m0 + row_a0 + 64) * K + cb;
    const unsigned short* bptr0 = W + (size_t)(n0 + row_a0) * K + cb;
    const unsigned short* bptr1 = W + (size_t)(n0 + row_a0 + 64) * K + cb;
    unsigned short* lA0 = &As[w * 512];
    unsigned short* lA1 = &As[2048 + w * 512];
    unsigned short* lB0 = &Bs[w * 512];
    unsigned short* lB1 = &Bs[2048 + w * 512];

    for (int k0 = 0; k0 < K; k0 += 32) {
        gload_lds16(aptr0 + k0, lA0);
        gload_lds16(aptr1 + k0, lA1);
        gload_lds16(bptr0 + k0, lB0);
        gload_lds16(bptr1 + k0, lB1);
        __syncthreads();

        bf16x8 af[4], bfr[4];
        #pragma unroll
        for (int i = 0; i < 4; ++i)
            af[i] = *reinterpret_cast<const bf16x8*>(&As[(wr * 64 + i * 16 + lr) * 32 + lk * 8]);
        #pragma unroll
        for (int j = 0; j < 4; ++j)
            bfr[j] = *reinterpret_cast<const bf16x8*>(&Bs[(wc * 64 + j * 16 + lr) * 32 + lk * 8]);
        #pragma unroll
        for (int i = 0; i < 4; ++i)
            #pragma unroll
            for (int j = 0; j < 4; ++j)
                acc[i][j] = __builtin_amdgcn_mfma_f32_16x16x32_bf16(af[i], bfr[j], acc[i][j], 0, 0, 0);
        __syncthreads();
    }

    #pragma unroll
    for (int i = 0; i < 4; ++i) {
        #pragma unroll
        for (int j = 0; j < 4; ++j) {
            int n = n0 + wc * 64 + j * 16 + lr;
            float ba = bias_a[n] + bias_b[n];
            int d = n >> 9, g = n & 511;
            #pragma unroll
            for (int r = 0; r < 4; ++r) {
                int m = m_base + m0 + wr * 64 + i * 16 + lk * 4 + r;
                Cout[((size_t)d * Mtot + m) * 512 + g] = acc[i][j][r] + ba;
            }
        }
    }
}

// ---------------------------------------------------------------------------
// BiLSTM recurrence: one block per (dir,batch). 1024 threads.
// ---------------------------------------------------------------------------
template <typename OT>
__global__ __launch_bounds__(1024) void lstm_kernel(
    const float* __restrict__ pre,   // [d][b][t][512]
    const float* __restrict__ Whh,   // [2][512][128]
    OT* __restrict__ hout)           // [b][t][256]
{
    const int d   = blockIdx.x >> 6;
    const int b   = blockIdx.x & 63;
    const int tid = threadIdx.x;
    const int g   = tid & 511;
    const int kh  = tid >> 9;

    float w[64];
    const float* wsrc = Whh + ((size_t)d * 512 + g) * 128 + kh * 64;
    #pragma unroll
    for (int k = 0; k < 64; ++k) w[k] = wsrc[k];

    __shared__ __align__(16) float h_lds[128];
    __shared__ float part[1024];
    __shared__ float gates[512];

    if (tid < 128) h_lds[tid] = 0.f;
    float c = 0.f;
    __syncthreads();

    const float* prebase = pre + ((size_t)(d * B_ + b)) * T_ * 512;

    for (int s = 0; s < T_; ++s) {
        int t = d ? (T_ - 1 - s) : s;
        float p = (tid < 512) ? prebase[(size_t)t * 512 + g] : 0.f;

        float acc0 = 0.f, acc1 = 0.f;
        #pragma unroll
        for (int k4 = 0; k4 < 16; ++k4) {
            float4 hv = *reinterpret_cast<const float4*>(&h_lds[kh * 64 + k4 * 4]);
            acc0 += w[k4 * 4 + 0] * hv.x; acc1 += w[k4 * 4 + 1] * hv.y;
            acc0 += w[k4 * 4 + 2] * hv.z; acc1 += w[k4 * 4 + 3] * hv.w;
        }
        part[tid] = acc0 + acc1;
        __syncthreads();
        if (tid < 512) gates[g] = p + part[g] + part[g + 512];
        __syncthreads();
        if (tid < 128) {
            float gi = gates[tid], gf = gates[tid + 128];
            float gc = gates[tid + 256], go = gates[tid + 384];
            c = sigmoidf_(gf) * c + sigmoidf_(gi) * tanhf(gc);
            float h = sigmoidf_(go) * tanhf(c);
            h_lds[tid] = h;
            store_h(&hout[((size_t)b * T_ + t) * 256 + d * 128 + tid], h);
        }
        __syncthreads();
    }
}

// ---------------------------------------------------------------------------
// attention scores: block per b.
// ---------------------------------------------------------------------------
__global__ __launch_bounds__(256) void attn_scores_kernel(
    const float* __restrict__ l1, const float* __restrict__ Wa1,
    const float* __restrict__ ba1, const float* __restrict__ Wa2,
    const float* __restrict__ ba2, float* __restrict__ scores)
{
    const int b   = blockIdx.x;
    const int tid = threadIdx.x;
    const int j   = tid & 63, kq = tid >> 6;

    float w[64];
    const float* wsrc = Wa1 + j * 256 + kq * 64;
    #pragma unroll
    for (int k = 0; k < 64; ++k) w[k] = wsrc[k];

    __shared__ __align__(16) float row[256];
    __shared__ float part[256];
    const float* lb  = l1 + (size_t)b * T_ * 256;
    float wa2 = (tid < 64) ? Wa2[tid] : 0.f;
    float bj  = (tid < 64) ? ba1[tid] : 0.f;
    float bb2 = ba2[0];

    for (int t = 0; t < T_; ++t) {
        __syncthreads();
        row[tid] = lb[(size_t)t * 256 + tid];
        __syncthreads();
        float acc = 0.f;
        #pragma unroll
        for (int k4 = 0; k4 < 16; ++k4) {
            float4 hv = *reinterpret_cast<const float4*>(&row[kq * 64 + k4 * 4]);
            acc += w[k4 * 4 + 0] * hv.x + w[k4 * 4 + 1] * hv.y
                 + w[k4 * 4 + 2] * hv.z + w[k4 * 4 + 3] * hv.w;
        }
        part[tid] = acc;
        __syncthreads();
        if (tid < 64) {
            float dj = part[tid] + part[tid + 64] + part[tid + 128] + part[tid + 192];
            float sv = tanhf(dj + bj) * wa2;
            #pragma unroll
            for (int off = 32; off > 0; off >>= 1) sv += __shfl_xor(sv, off);
            if (tid == 0) scores[b * T_ + t] = sv + bb2;
        }
    }
}

// ---------------------------------------------------------------------------
// softmax + context + classifier head: block per b.
// ---------------------------------------------------------------------------
__global__ __launch_bounds__(256) void attn_head_kernel(
    const float* __restrict__ l1, const float* __restrict__ scores,
    const float* __restrict__ Wc1, const float* __restrict__ bc1,
    const float* __restrict__ Wc2, const float* __restrict__ bc2,
    float* __restrict__ out)
{
    const int b   = blockIdx.x;
    const int tid = threadIdx.x;
    __shared__ float wsl[256];
    __shared__ float red[8];
    __shared__ float ctx[256];
    __shared__ float hid[128];
    __shared__ float wc1s[128 * 65];

    float v = scores[b * T_ + tid];
    float mx = v;
    #pragma unroll
    for (int off = 32; off > 0; off >>= 1) mx = fmaxf(mx, __shfl_xor(mx, off));
    if ((tid & 63) == 0) red[tid >> 6] = mx;
    __syncthreads();
    mx = fmaxf(fmaxf(red[0], red[1]), fmaxf(red[2], red[3]));
    float e = expf(v - mx);
    float s = e;
    #pragma unroll
    for (int off = 32; off > 0; off >>= 1) s += __shfl_xor(s, off);
    if ((tid & 63) == 0) red[4 + (tid >> 6)] = s;
    __syncthreads();
    float denom = red[4] + red[5] + red[6] + red[7];
    wsl[tid] = e / denom;
    __syncthreads();

    float acc = 0.f;
    const float* lb = l1 + (size_t)b * T_ * 256 + tid;
    #pragma unroll 4
    for (int t = 0; t < T_; ++t) acc += lb[(size_t)t * 256] * wsl[t];
    ctx[tid] = acc;
    __syncthreads();

    float hacc = (tid < 128) ? bc1[tid] : 0.f;
    for (int kb = 0; kb < 4; ++kb) {
        for (int i = tid; i < 128 * 64; i += 256) {
            int jj = i >> 6, kk = i & 63;
            wc1s[jj * 65 + kk] = Wc1[jj * 256 + kb * 64 + kk];
        }
        __syncthreads();
        if (tid < 128) {
            #pragma unroll
            for (int kk = 0; kk < 64; ++kk)
                hacc += ctx[kb * 64 + kk] * wc1s[tid * 65 + kk];
        }
        __syncthreads();
    }
    if (tid < 128) hid[tid] = fmaxf(hacc, 0.f);
    __syncthreads();

    if (tid < NC_) {
        float a = bc2[tid];
        #pragma unroll
        for (int k = 0; k < 128; ++k) a += hid[k] * Wc2[tid * 128 + k];
        out[b * NC_ + tid] = a;
    }
}

// ---------------------------------------------------------------------------
extern "C" void kernel_launch(void* const* d_in, const int* in_sizes, int n_in,
                              void* d_out, int out_size, void* d_ws, size_t ws_size,
                              hipStream_t stream)
{
    const float* x    = (const float*)d_in[0];
    const float* adj  = (const float*)d_in[1];
    const float* Wg1  = (const float*)d_in[2];
    const float* bg1  = (const float*)d_in[3];
    const float* Wg2  = (const float*)d_in[4];
    const float* bg2  = (const float*)d_in[5];
    const float* Wih0 = (const float*)d_in[6];
    const float* Whh0 = (const float*)d_in[7];
    const float* bih0 = (const float*)d_in[8];
    const float* bhh0 = (const float*)d_in[9];
    const float* Wih1 = (const float*)d_in[10];
    const float* Whh1 = (const float*)d_in[11];
    const float* bih1 = (const float*)d_in[12];
    const float* bhh1 = (const float*)d_in[13];
    const float* Wa1  = (const float*)d_in[14];
    const float* ba1  = (const float*)d_in[15];
    const float* Wa2  = (const float*)d_in[16];
    const float* ba2  = (const float*)d_in[17];
    const float* Wc1  = (const float*)d_in[18];
    const float* bc1  = (const float*)d_in[19];
    const float* Wc2  = (const float*)d_in[20];
    const float* bc2  = (const float*)d_in[21];

    char* ws = (char*)d_ws;
    // Workspace (bytes). Peak 156,422,144 < 160,432,128 proven by round-1 pass.
    //  seqb [0, 63,963,136)           chunk-local GCN output (bf16)
    //  l0b  [0, 8,388,608)            phase-2 reuse
    //  l1f  [8,388,608, 25,165,824)   phase-3 reuse
    //  scr  [25,165,824, +64K)
    //  H1W  [64,000,000, 80,777,216)  sub-chunk H1 transposed bf16
    //  adjb [80,777,216, +8192)  w2b [80,785,408, +8192)
    //  pre  [80,793,600, 147,902,464)
    //  W0b  [147,902,464, 155,897,856)  W1b [155,897,856, 156,422,144)
    unsigned short* seqb = (unsigned short*)(ws);
    unsigned short* l0b  = (unsigned short*)(ws);
    float*          l1f  = (float*)(ws + 8388608);
    float*          scr  = (float*)(ws + 25165824);
    unsigned short* H1W  = (unsigned short*)(ws + 64000000);
    unsigned short* adjb = (unsigned short*)(ws + 80777216);
    unsigned short* w2b  = (unsigned short*)(ws + 80785408);
    float*          pre  = (float*)(ws + 80793600);
    unsigned short* W0b  = (unsigned short*)(ws + 147902464);
    unsigned short* W1b  = (unsigned short*)(ws + 155897856);

    const int n0e = in_sizes[6];    // 2*512*3904
    const int n1e = in_sizes[10];   // 2*512*256
    cvt_bf16_kernel<<<(n0e / 4 + 255) / 256, 256, 0, stream>>>(Wih0, W0b, n0e / 4);
    cvt_bf16_kernel<<<(n1e / 4 + 255) / 256, 256, 0, stream>>>(Wih1, W1b, n1e / 4);
    cvt_adj_kernel<<<16, 256, 0, stream>>>(adj, adjb);
    cvt_w2_kernel <<<16, 256, 0, stream>>>(Wg2, w2b);

    for (int ch = 0; ch < 2; ++ch) {
        int m_base = ch * CHUNK_M;
        for (int sc = 0; sc < CHUNK_M / SUB_M; ++sc) {
            gcn_h1_kernel<<<SUB_M, 256, 0, stream>>>(
                x, adj, Wg1, bg1, H1W, m_base + sc * SUB_M);
            gcn_mix_kernel<<<SUB_M / 2, 256, 0, stream>>>(
                H1W, adjb, w2b, bg2, seqb, sc * SUB_M);
        }
        gemm_mfma_kernel<<<dim3(CHUNK_M / 128, 8), 256, 0, stream>>>(
            seqb, W0b, bih0, bhh0, pre, NG_, m_base, M_TOT);
    }
    lstm_kernel<<<128, 1024, 0, stream>>>(pre, Whh0, l0b);
    gemm_mfma_kernel<<<dim3(M_TOT / 128, 8), 256, 0, stream>>>(
        l0b, W1b, bih1, bhh1, pre, 256, 0, M_TOT);
    lstm_kernel<<<128, 1024, 0, stream>>>(pre, Whh1, l1f);
    attn_scores_kernel<<<B_, 256, 0, stream>>>(l1f, Wa1, ba1, Wa2, ba2, scr);
    attn_head_kernel<<<B_, 256, 0, stream>>>(l1f, scr, Wc1, bc1, Wc2, bc2, (float*)d_out);
}

// Round 9
// 1084.584 us; speedup vs baseline: 2.4389x; 1.2668x over previous
//
#include <hip/hip_runtime.h>
#include <math.h>

#define B_    64
#define T_    256
#define N_    61
#define FIN_  3
#define GH_   64
#define LH_   128
#define NC_   10
#define NG_   3904      /* N_*GH_ */
#define M_TOT 16384     /* B_*T_  */
#define CHUNK_M 8192
#define SUB_M   2048    /* GCN sub-chunk */

typedef __attribute__((ext_vector_type(8))) short bf16x8;
typedef __attribute__((ext_vector_type(4))) float f32x4;

__device__ __forceinline__ float gelu_exact(float x) {
    return 0.5f * x * (1.0f + erff(x * 0.70710678118654752f));
}
__device__ __forceinline__ float sigmoidf_(float x) {
    return 1.0f / (1.0f + expf(-x));
}
__device__ __forceinline__ unsigned short f2bf(float f) {
    unsigned int u = __float_as_uint(f);
    u = (u + 0x7FFFu + ((u >> 16) & 1u)) >> 16;
    return (unsigned short)u;
}
__device__ __forceinline__ void store_h(float* p, float v) { *p = v; }
__device__ __forceinline__ void store_h(unsigned short* p, float v) { *p = f2bf(v); }

__device__ __forceinline__ void gload_lds16(const void* g, void* l) {
    __builtin_amdgcn_global_load_lds(
        (const __attribute__((address_space(1))) unsigned int*)g,
        (__attribute__((address_space(3))) unsigned int*)l,
        16, 0, 0);
}

// Shared 64-elem-row swizzle: XOR k with (row&3)*16. Used identically by every
// writer (global pre-swizzle) and reader (LDS frag read) — both-sides-or-neither.
__device__ __forceinline__ int swz(int row, int k) { return k ^ ((row & 3) << 4); }

// ---------------------------------------------------------------------------
// fp32 -> bf16 weight conversion (4 elems/thread). n4 = ELEMENT count / 4.
// ---------------------------------------------------------------------------
__global__ __launch_bounds__(256) void cvt_bf16_kernel(
    const float* __restrict__ in, unsigned short* __restrict__ out, int n4)
{
    int i = blockIdx.x * 256 + threadIdx.x;
    if (i < n4) {
        float4 v = reinterpret_cast<const float4*>(in)[i];
        ushort4 o;
        o.x = f2bf(v.x); o.y = f2bf(v.y); o.z = f2bf(v.z); o.w = f2bf(v.w);
        reinterpret_cast<ushort4*>(out)[i] = o;
    }
}

// adj (61x61 fp32) -> adjb (64x64 bf16, zero-padded, pre-swizzled). grid 16.
__global__ __launch_bounds__(256) void cvt_adj_kernel(
    const float* __restrict__ adj, unsigned short* __restrict__ adjb)
{
    int i = blockIdx.x * 256 + threadIdx.x;
    if (i < 4096) {
        int n = i >> 6, m = i & 63;
        unsigned short v = (n < N_ && m < N_) ? f2bf(adj[n * N_ + m]) : (unsigned short)0;
        adjb[n * 64 + swz(n, m)] = v;
    }
}

// W2 (64x64 fp32) -> w2b (64x64 bf16, pre-swizzled). grid 16.
__global__ __launch_bounds__(256) void cvt_w2_kernel(
    const float* __restrict__ W2, unsigned short* __restrict__ w2b)
{
    int i = blockIdx.x * 256 + threadIdx.x;
    if (i < 4096) {
        int c = i >> 6, f = i & 63;
        w2b[c * 64 + swz(c, f)] = f2bf(W2[c * 64 + f]);
    }
}

// ---------------------------------------------------------------------------
// GCN K1: per (b,t): AX = A@X (fp32), H1 = gelu(AX @ W1^T + b1).
// Writes H1W bf16 TRANSPOSED [btl*64+c][m], m=61..63 zeroed, pre-swizzled.
// grid = SUB_M blocks.
// ---------------------------------------------------------------------------
__global__ __launch_bounds__(256) void gcn_h1_kernel(
    const float* __restrict__ x, const float* __restrict__ adj,
    const float* __restrict__ W1, const float* __restrict__ b1,
    unsigned short* __restrict__ H1W, int bt_base)
{
    __shared__ float adjs[N_ * 65];   // stride 65: conflict-free column walks
    __shared__ float h1s [N_ * 65];
    __shared__ float xs [184];
    __shared__ float axs[184];
    __shared__ float w1s[192];
    __shared__ float b1s[64];

    const int tid = threadIdx.x;
    const int bt  = bt_base + blockIdx.x;

    for (int i = tid; i < N_ * N_; i += 256) {
        int n = i / 61, m = i - n * 61;
        adjs[n * 65 + m] = adj[i];
    }
    for (int i = tid; i < N_ * FIN_; i += 256) xs[i] = x[(size_t)bt * (N_ * FIN_) + i];
    for (int i = tid; i < GH_ * FIN_; i += 256) w1s[i] = W1[i];
    if (tid < GH_) b1s[tid] = b1[tid];
    __syncthreads();

    if (tid < N_ * FIN_) {
        int n = tid / 3, f = tid - n * 3;
        float acc = 0.f;
        for (int m = 0; m < N_; ++m) acc += adjs[n * 65 + m] * xs[m * 3 + f];
        axs[tid] = acc;
    }
    __syncthreads();

    for (int u = 0; u < 16; ++u) {
        int idx = tid + u * 256;
        if (idx < N_ * GH_) {
            int m = idx >> 6, c = idx & 63;
            float acc = b1s[c];
            acc += axs[m * 3 + 0] * w1s[c * 3 + 0];
            acc += axs[m * 3 + 1] * w1s[c * 3 + 1];
            acc += axs[m * 3 + 2] * w1s[c * 3 + 2];
            h1s[m * 65 + c] = gelu_exact(acc);
        }
    }
    __syncthreads();

    // transposed, padded, pre-swizzled write: H1W[(btl*64+c)][swz(c,m)]
    unsigned short* dst = H1W + (size_t)blockIdx.x * 4096;
    for (int i = tid; i < 4096; i += 256) {
        int c = i >> 6, m = i & 63;
        unsigned short v = (m < N_) ? f2bf(h1s[m * 65 + c]) : (unsigned short)0;
        dst[c * 64 + swz(c, m)] = v;
    }
}

// ---------------------------------------------------------------------------
// GCN K23: per block = 2 consecutive bt. MFMA both heavy stages:
//   stage1: AH1[n][btc] = adjb(64x64) @ H1W-tile^T
//   bounce: AH1 -> T[(btl*64+n)][c] bf16 (swizzled)
//   stage2: seq = gelu(T @ W2^T + b2)
// grid = SUB_M/2 blocks, 256 threads (4 waves).
// ---------------------------------------------------------------------------
__global__ __launch_bounds__(256) void gcn_mix_kernel(
    const unsigned short* __restrict__ H1W,   // [SUB_M*64][64] pre-swizzled
    const unsigned short* __restrict__ adjb,  // [64][64] pre-swizzled
    const unsigned short* __restrict__ w2b,   // [64][64] pre-swizzled
    const float* __restrict__ b2,
    unsigned short* __restrict__ seqc,        // chunk-local [CHUNK_M][3904]
    int sc_base)                              // sub-chunk base within chunk
{
    __shared__ unsigned short adjbs[64 * 64];   // 8 KB
    __shared__ unsigned short b1t [128 * 64];   // 16 KB (H1W rows for 2 bt)
    __shared__ unsigned short w2bs[64 * 64];    // 8 KB
    __shared__ unsigned short T   [128 * 64];   // 16 KB (AH1 transposed)
    __shared__ float b2s[64];

    const int tid = threadIdx.x;
    const int w   = tid >> 6;
    const int l   = tid & 63;
    const int lr  = l & 15, lk = l >> 4;
    const int p   = blockIdx.x;               // bt pair

    // staging: linear copies (sources are pre-swizzled in global)
    #pragma unroll
    for (int q = 0; q < 2; ++q)
        gload_lds16(adjb + q * 2048 + w * 512 + l * 8, &adjbs[q * 2048 + w * 512]);
    #pragma unroll
    for (int q = 0; q < 2; ++q)
        gload_lds16(w2b + q * 2048 + w * 512 + l * 8, &w2bs[q * 2048 + w * 512]);
    #pragma unroll
    for (int q = 0; q < 4; ++q)
        gload_lds16(H1W + (size_t)p * 8192 + q * 2048 + w * 512 + l * 8,
                    &b1t[q * 2048 + w * 512]);
    if (tid < 64) b2s[tid] = b2[tid];
    __syncthreads();

    // ---- stage1: AH1[n][col], wave w owns cols w*32..w*32+31
    f32x4 acc1[4][2];
    #pragma unroll
    for (int i = 0; i < 4; ++i)
        #pragma unroll
        for (int j = 0; j < 2; ++j) acc1[i][j] = (f32x4){0.f, 0.f, 0.f, 0.f};

    #pragma unroll
    for (int kk = 0; kk < 2; ++kk) {
        const int kb = kk * 32 + lk * 8;
        bf16x8 af[4], bfr[2];
        #pragma unroll
        for (int i = 0; i < 4; ++i) {
            int rn = i * 16 + lr;
            af[i] = *reinterpret_cast<const bf16x8*>(&adjbs[rn * 64 + swz(rn, kb)]);
        }
        #pragma unroll
        for (int j = 0; j < 2; ++j) {
            int rb = w * 32 + j * 16 + lr;
            bfr[j] = *reinterpret_cast<const bf16x8*>(&b1t[rb * 64 + swz(rb, kb)]);
        }
        #pragma unroll
        for (int i = 0; i < 4; ++i)
            #pragma unroll
            for (int j = 0; j < 2; ++j)
                acc1[i][j] = __builtin_amdgcn_mfma_f32_16x16x32_bf16(af[i], bfr[j], acc1[i][j], 0, 0, 0);
    }

    // ---- bounce: AH1[n][col] -> T[(col>>6)*64 + n][col&63], bf16, swizzled.
    #pragma unroll
    for (int i = 0; i < 4; ++i) {
        #pragma unroll
        for (int j = 0; j < 2; ++j) {
            int col = w * 32 + j * 16 + lr;
            int c   = col & 63;
            int rbase = (col >> 6) * 64;
            #pragma unroll
            for (int r = 0; r < 4; ++r) {
                int n   = i * 16 + lk * 4 + r;
                int row = rbase + n;
                T[row * 64 + swz(row, c)] = f2bf(acc1[i][j][r]);
            }
        }
    }
    __syncthreads();

    // ---- stage2: rows (bt,n) = w*32.., cols cout
    f32x4 acc2[2][4];
    #pragma unroll
    for (int i = 0; i < 2; ++i)
        #pragma unroll
        for (int j = 0; j < 4; ++j) acc2[i][j] = (f32x4){0.f, 0.f, 0.f, 0.f};

    #pragma unroll
    for (int kk = 0; kk < 2; ++kk) {
        const int kb = kk * 32 + lk * 8;
        bf16x8 a2[2], bw[4];
        #pragma unroll
        for (int i = 0; i < 2; ++i) {
            int r2 = w * 32 + i * 16 + lr;
            a2[i] = *reinterpret_cast<const bf16x8*>(&T[r2 * 64 + swz(r2, kb)]);
        }
        #pragma unroll
        for (int j = 0; j < 4; ++j) {
            int co = j * 16 + lr;
            bw[j] = *reinterpret_cast<const bf16x8*>(&w2bs[co * 64 + swz(co, kb)]);
        }
        #pragma unroll
        for (int i = 0; i < 2; ++i)
            #pragma unroll
            for (int j = 0; j < 4; ++j)
                acc2[i][j] = __builtin_amdgcn_mfma_f32_16x16x32_bf16(a2[i], bw[j], acc2[i][j], 0, 0, 0);
    }

    // ---- epilogue: +b2, gelu, write seq rows (n<61 guard)
    #pragma unroll
    for (int i = 0; i < 2; ++i) {
        #pragma unroll
        for (int j = 0; j < 4; ++j) {
            int co = j * 16 + lr;
            float bias = b2s[co];
            #pragma unroll
            for (int r = 0; r < 4; ++r) {
                int row = w * 32 + i * 16 + lk * 4 + r;
                int n   = row & 63;
                if (n < N_) {
                    int btc = sc_base + p * 2 + (row >> 6);
                    seqc[(size_t)btc * NG_ + n * 64 + co] =
                        f2bf(gelu_exact(acc2[i][j][r] + bias));
                }
            }
        }
    }
}

// ---------------------------------------------------------------------------
// bf16 MFMA GEMM: C = A(Mc x K) @ W(1024 x K)^T + bias_a + bias_b
// 128x128 tile, 4 waves (2x2), 16x16x32 MFMA, BK=32, global_load_lds staging.
// Output scattered fp32 to [d][Mtot][512].
// ---------------------------------------------------------------------------
__global__ __launch_bounds__(256) void gemm_mfma_kernel(
    const unsigned short* __restrict__ A, const unsigned short* __restrict__ W,
    const float* __restrict__ bias_a, const float* __restrict__ bias_b,
    float* __restrict__ Cout, int K, int m_base, int Mtot)
{
    __shared__ unsigned short As[128 * 32];   // 8 KB, row-major [row][k], 64B/row
    __shared__ unsigned short Bs[128 * 32];   // 8 KB

    const int tid = threadIdx.x;
    const int w   = tid >> 6;
    const int l   = tid & 63;
    const int wr  = w >> 1, wc = w & 1;
    const int lr  = l & 15, lk = l >> 4;

    const int m0 = blockIdx.x * 128;
    const int n0 = blockIdx.y * 128;

    f32x4 acc[4][4];
    #pragma unroll
    for (int i = 0; i < 4; ++i)
        #pragma unroll
        for (int j = 0; j < 4; ++j) acc[i][j] = (f32x4){0.f, 0.f, 0.f, 0.f};

    const int row_a0 = tid >> 2;
    const int cb     = (tid & 3) * 8;
    const unsigned short* aptr0 = A + (size_t)(m0 + row_a0) * K + cb;
    const unsigned short* aptr1 = A + (size_t)(m0 + row_a0 + 64) * K + cb;
    const unsigned short* bptr0 = W + (size_t)(n0 + row_a0) * K + cb;
    const unsigned short* bptr1 = W + (size_t)(n0 + row_a0 + 64) * K + cb;
    unsigned short* lA0 = &As[w * 512];
    unsigned short* lA1 = &As[2048 + w * 512];
    unsigned short* lB0 = &Bs[w * 512];
    unsigned short* lB1 = &Bs[2048 + w * 512];

    for (int k0 = 0; k0 < K; k0 += 32) {
        gload_lds16(aptr0 + k0, lA0);
        gload_lds16(aptr1 + k0, lA1);
        gload_lds16(bptr0 + k0, lB0);
        gload_lds16(bptr1 + k0, lB1);
        __syncthreads();

        bf16x8 af[4], bfr[4];
        #pragma unroll
        for (int i = 0; i < 4; ++i)
            af[i] = *reinterpret_cast<const bf16x8*>(&As[(wr * 64 + i * 16 + lr) * 32 + lk * 8]);
        #pragma unroll
        for (int j = 0; j < 4; ++j)
            bfr[j] = *reinterpret_cast<const bf16x8*>(&Bs[(wc * 64 + j * 16 + lr) * 32 + lk * 8]);
        #pragma unroll
        for (int i = 0; i < 4; ++i)
            #pragma unroll
            for (int j = 0; j < 4; ++j)
                acc[i][j] = __builtin_amdgcn_mfma_f32_16x16x32_bf16(af[i], bfr[j], acc[i][j], 0, 0, 0);
        __syncthreads();
    }

    #pragma unroll
    for (int i = 0; i < 4; ++i) {
        #pragma unroll
        for (int j = 0; j < 4; ++j) {
            int n = n0 + wc * 64 + j * 16 + lr;
            float ba = bias_a[n] + bias_b[n];
            int d = n >> 9, g = n & 511;
            #pragma unroll
            for (int r = 0; r < 4; ++r) {
                int m = m_base + m0 + wr * 64 + i * 16 + lk * 4 + r;
                Cout[((size_t)d * Mtot + m) * 512 + g] = acc[i][j][r] + ba;
            }
        }
    }
}

// ---------------------------------------------------------------------------
// BiLSTM recurrence: one block per (dir,batch). 1024 threads.
// ---------------------------------------------------------------------------
template <typename OT>
__global__ __launch_bounds__(1024) void lstm_kernel(
    const float* __restrict__ pre,   // [d][b][t][512]
    const float* __restrict__ Whh,   // [2][512][128]
    OT* __restrict__ hout)           // [b][t][256]
{
    const int d   = blockIdx.x >> 6;
    const int b   = blockIdx.x & 63;
    const int tid = threadIdx.x;
    const int g   = tid & 511;
    const int kh  = tid >> 9;

    float w[64];
    const float* wsrc = Whh + ((size_t)d * 512 + g) * 128 + kh * 64;
    #pragma unroll
    for (int k = 0; k < 64; ++k) w[k] = wsrc[k];

    __shared__ __align__(16) float h_lds[128];
    __shared__ float part[1024];
    __shared__ float gates[512];

    if (tid < 128) h_lds[tid] = 0.f;
    float c = 0.f;
    __syncthreads();

    const float* prebase = pre + ((size_t)(d * B_ + b)) * T_ * 512;

    for (int s = 0; s < T_; ++s) {
        int t = d ? (T_ - 1 - s) : s;
        float p = (tid < 512) ? prebase[(size_t)t * 512 + g] : 0.f;

        float acc0 = 0.f, acc1 = 0.f;
        #pragma unroll
        for (int k4 = 0; k4 < 16; ++k4) {
            float4 hv = *reinterpret_cast<const float4*>(&h_lds[kh * 64 + k4 * 4]);
            acc0 += w[k4 * 4 + 0] * hv.x; acc1 += w[k4 * 4 + 1] * hv.y;
            acc0 += w[k4 * 4 + 2] * hv.z; acc1 += w[k4 * 4 + 3] * hv.w;
        }
        part[tid] = acc0 + acc1;
        __syncthreads();
        if (tid < 512) gates[g] = p + part[g] + part[g + 512];
        __syncthreads();
        if (tid < 128) {
            float gi = gates[tid], gf = gates[tid + 128];
            float gc = gates[tid + 256], go = gates[tid + 384];
            c = sigmoidf_(gf) * c + sigmoidf_(gi) * tanhf(gc);
            float h = sigmoidf_(go) * tanhf(c);
            h_lds[tid] = h;
            store_h(&hout[((size_t)b * T_ + t) * 256 + d * 128 + tid], h);
        }
        __syncthreads();
    }
}

// ---------------------------------------------------------------------------
// attention scores: block per (b, 32-t tile). Rows staged in LDS once;
// grid (64,8) = 512 blocks — fixes the 2.9%-occupancy latency chain.
// ---------------------------------------------------------------------------
__global__ __launch_bounds__(256) void attn_scores_kernel(
    const float* __restrict__ l1, const float* __restrict__ Wa1,
    const float* __restrict__ ba1, const float* __restrict__ Wa2,
    const float* __restrict__ ba2, float* __restrict__ scores)
{
    const int b   = blockIdx.x;
    const int t0  = blockIdx.y * 32;
    const int tid = threadIdx.x;
    const int j   = tid & 63, kq = tid >> 6;

    float w[64];
    const float* wsrc = Wa1 + j * 256 + kq * 64;
    #pragma unroll
    for (int k = 0; k < 64; ++k) w[k] = wsrc[k];

    __shared__ __align__(16) float rows[32 * 256];   // 32 KB
    __shared__ float part[256];

    // stage 32 rows: 2048 float4, 8 per thread, coalesced
    const float4* src = reinterpret_cast<const float4*>(
        l1 + (size_t)b * T_ * 256 + (size_t)t0 * 256);
    float4* dstv = reinterpret_cast<float4*>(rows);
    #pragma unroll
    for (int q = 0; q < 8; ++q) dstv[q * 256 + tid] = src[q * 256 + tid];

    float wa2 = (tid < 64) ? Wa2[tid] : 0.f;
    float bj  = (tid < 64) ? ba1[tid] : 0.f;
    float bb2 = ba2[0];
    __syncthreads();

    for (int tl = 0; tl < 32; ++tl) {
        const float* row = &rows[tl * 256 + kq * 64];
        float acc = 0.f;
        #pragma unroll
        for (int k4 = 0; k4 < 16; ++k4) {
            float4 hv = *reinterpret_cast<const float4*>(&row[k4 * 4]);
            acc += w[k4 * 4 + 0] * hv.x + w[k4 * 4 + 1] * hv.y
                 + w[k4 * 4 + 2] * hv.z + w[k4 * 4 + 3] * hv.w;
        }
        part[tid] = acc;
        __syncthreads();
        if (tid < 64) {
            float dj = part[tid] + part[tid + 64] + part[tid + 128] + part[tid + 192];
            float sv = tanhf(dj + bj) * wa2;
            #pragma unroll
            for (int off = 32; off > 0; off >>= 1) sv += __shfl_xor(sv, off);
            if (tid == 0) scores[b * T_ + t0 + tl] = sv + bb2;
        }
        __syncthreads();
    }
}

// ---------------------------------------------------------------------------
// softmax + context + classifier head: block per b.
// ---------------------------------------------------------------------------
__global__ __launch_bounds__(256) void attn_head_kernel(
    const float* __restrict__ l1, const float* __restrict__ scores,
    const float* __restrict__ Wc1, const float* __restrict__ bc1,
    const float* __restrict__ Wc2, const float* __restrict__ bc2,
    float* __restrict__ out)
{
    const int b   = blockIdx.x;
    const int tid = threadIdx.x;
    __shared__ float wsl[256];
    __shared__ float red[8];
    __shared__ float ctx[256];
    __shared__ float hid[128];
    __shared__ float wc1s[128 * 65];

    float v = scores[b * T_ + tid];
    float mx = v;
    #pragma unroll
    for (int off = 32; off > 0; off >>= 1) mx = fmaxf(mx, __shfl_xor(mx, off));
    if ((tid & 63) == 0) red[tid >> 6] = mx;
    __syncthreads();
    mx = fmaxf(fmaxf(red[0], red[1]), fmaxf(red[2], red[3]));
    float e = expf(v - mx);
    float s = e;
    #pragma unroll
    for (int off = 32; off > 0; off >>= 1) s += __shfl_xor(s, off);
    if ((tid & 63) == 0) red[4 + (tid >> 6)] = s;
    __syncthreads();
    float denom = red[4] + red[5] + red[6] + red[7];
    wsl[tid] = e / denom;
    __syncthreads();

    float acc = 0.f;
    const float* lb = l1 + (size_t)b * T_ * 256 + tid;
    #pragma unroll 4
    for (int t = 0; t < T_; ++t) acc += lb[(size_t)t * 256] * wsl[t];
    ctx[tid] = acc;
    __syncthreads();

    float hacc = (tid < 128) ? bc1[tid] : 0.f;
    for (int kb = 0; kb < 4; ++kb) {
        for (int i = tid; i < 128 * 64; i += 256) {
            int jj = i >> 6, kk = i & 63;
            wc1s[jj * 65 + kk] = Wc1[jj * 256 + kb * 64 + kk];
        }
        __syncthreads();
        if (tid < 128) {
            #pragma unroll
            for (int kk = 0; kk < 64; ++kk)
                hacc += ctx[kb * 64 + kk] * wc1s[tid * 65 + kk];
        }
        __syncthreads();
    }
    if (tid < 128) hid[tid] = fmaxf(hacc, 0.f);
    __syncthreads();

    if (tid < NC_) {
        float a = bc2[tid];
        #pragma unroll
        for (int k = 0; k < 128; ++k) a += hid[k] * Wc2[tid * 128 + k];
        out[b * NC_ + tid] = a;
    }
}

// ---------------------------------------------------------------------------
extern "C" void kernel_launch(void* const* d_in, const int* in_sizes, int n_in,
                              void* d_out, int out_size, void* d_ws, size_t ws_size,
                              hipStream_t stream)
{
    const float* x    = (const float*)d_in[0];
    const float* adj  = (const float*)d_in[1];
    const float* Wg1  = (const float*)d_in[2];
    const float* bg1  = (const float*)d_in[3];
    const float* Wg2  = (const float*)d_in[4];
    const float* bg2  = (const float*)d_in[5];
    const float* Wih0 = (const float*)d_in[6];
    const float* Whh0 = (const float*)d_in[7];
    const float* bih0 = (const float*)d_in[8];
    const float* bhh0 = (const float*)d_in[9];
    const float* Wih1 = (const float*)d_in[10];
    const float* Whh1 = (const float*)d_in[11];
    const float* bih1 = (const float*)d_in[12];
    const float* bhh1 = (const float*)d_in[13];
    const float* Wa1  = (const float*)d_in[14];
    const float* ba1  = (const float*)d_in[15];
    const float* Wa2  = (const float*)d_in[16];
    const float* ba2  = (const float*)d_in[17];
    const float* Wc1  = (const float*)d_in[18];
    const float* bc1  = (const float*)d_in[19];
    const float* Wc2  = (const float*)d_in[20];
    const float* bc2  = (const float*)d_in[21];

    char* ws = (char*)d_ws;
    // Workspace (bytes). Peak 156,422,144 < 160,432,128 proven by round-1 pass.
    unsigned short* seqb = (unsigned short*)(ws);
    unsigned short* l0b  = (unsigned short*)(ws);
    float*          l1f  = (float*)(ws + 8388608);
    float*          scr  = (float*)(ws + 25165824);
    unsigned short* H1W  = (unsigned short*)(ws + 64000000);
    unsigned short* adjb = (unsigned short*)(ws + 80777216);
    unsigned short* w2b  = (unsigned short*)(ws + 80785408);
    float*          pre  = (float*)(ws + 80793600);
    unsigned short* W0b  = (unsigned short*)(ws + 147902464);
    unsigned short* W1b  = (unsigned short*)(ws + 155897856);

    const int n0e = in_sizes[6];    // 2*512*3904
    const int n1e = in_sizes[10];   // 2*512*256
    cvt_bf16_kernel<<<(n0e / 4 + 255) / 256, 256, 0, stream>>>(Wih0, W0b, n0e / 4);
    cvt_bf16_kernel<<<(n1e / 4 + 255) / 256, 256, 0, stream>>>(Wih1, W1b, n1e / 4);
    cvt_adj_kernel<<<16, 256, 0, stream>>>(adj, adjb);
    cvt_w2_kernel <<<16, 256, 0, stream>>>(Wg2, w2b);

    for (int ch = 0; ch < 2; ++ch) {
        int m_base = ch * CHUNK_M;
        for (int sc = 0; sc < CHUNK_M / SUB_M; ++sc) {
            gcn_h1_kernel<<<SUB_M, 256, 0, stream>>>(
                x, adj, Wg1, bg1, H1W, m_base + sc * SUB_M);
            gcn_mix_kernel<<<SUB_M / 2, 256, 0, stream>>>(
                H1W, adjb, w2b, bg2, seqb, sc * SUB_M);
        }
        gemm_mfma_kernel<<<dim3(CHUNK_M / 128, 8), 256, 0, stream>>>(
            seqb, W0b, bih0, bhh0, pre, NG_, m_base, M_TOT);
    }
    lstm_kernel<<<128, 1024, 0, stream>>>(pre, Whh0, l0b);
    gemm_mfma_kernel<<<dim3(M_TOT / 128, 8), 256, 0, stream>>>(
        l0b, W1b, bih1, bhh1, pre, 256, 0, M_TOT);
    lstm_kernel<<<128, 1024, 0, stream>>>(pre, Whh1, l1f);
    attn_scores_kernel<<<dim3(B_, 8), 256, 0, stream>>>(l1f, Wa1, ba1, Wa2, ba2, scr);
    attn_head_kernel<<<B_, 256, 0, stream>>>(l1f, scr, Wc1, bc1, Wc2, bc2, (float*)d_out);
}